// Round 5
// baseline (299.498 us; speedup 1.0000x reference)
//
#include <hip/hip_runtime.h>
#include <hip/hip_bf16.h>
#include <stdint.h>

// CrissCrossAttention, MI355X gfx950.
// out = 2 * row-attention (column branch collapses exactly onto row branch).
// Pipeline: cvt x->bf16 | transpose W->bf16 | fused QKV GEMM | per-(b,h,r) MFMA
//           attention | GEMM(+bias) -> fp32 out.
// r5: XCD-aware block swizzle (r4 FETCH=141MB vs 35MB ideal: A-tiles re-fetched
//     across non-coherent per-XCD L2s) + 256-wide QKV tile (2x MFMA per barrier).

typedef __bf16 bf16_t;
typedef __bf16 bf16x4v __attribute__((ext_vector_type(4)));
typedef __bf16 bf16x8 __attribute__((ext_vector_type(8)));
typedef float  f32x4  __attribute__((ext_vector_type(4)));

#define GLD16(gp, lp)                                                                  \
  __builtin_amdgcn_global_load_lds((__attribute__((address_space(1))) const void*)(gp),\
                                   (__attribute__((address_space(3))) void*)(lp),      \
                                   16, 0, 0)

__device__ __forceinline__ float  bf2f(bf16_t x) { return (float)x; }
__device__ __forceinline__ bf16_t f2bf(float x)  { return (bf16_t)x; }

// ---------------------------------------------------------------------------
// fp32 -> bf16 conversion, float4 loads.
// ---------------------------------------------------------------------------
__global__ __launch_bounds__(256) void cvt_x(const float* __restrict__ X,
                                             bf16_t* __restrict__ Y, int n4)
{
  int i = blockIdx.x * blockDim.x + threadIdx.x;
  if (i < n4) {
    float4 v = ((const float4*)X)[i];
    bf16x4v o;
    o[0] = f2bf(v.x); o[1] = f2bf(v.y); o[2] = f2bf(v.z); o[3] = f2bf(v.w);
    ((bf16x4v*)Y)[i] = o;
  }
}

// ---------------------------------------------------------------------------
// Weight transpose + cast: WT[n][k] = (bf16)W[k][n], 512x512, z selects matrix.
// ---------------------------------------------------------------------------
__global__ void wt_kernel(const float* __restrict__ Wq, const float* __restrict__ Wk,
                          const float* __restrict__ Wv, const float* __restrict__ Wo,
                          bf16_t* __restrict__ WT)
{
  __shared__ bf16_t tile[32][33];
  const int mat = blockIdx.z;
  const float* W = (mat == 0) ? Wq : (mat == 1) ? Wk : (mat == 2) ? Wv : Wo;
  bf16_t* dst = WT + (size_t)mat * 262144;
  const int tx = threadIdx.x, ty = threadIdx.y;          // 32 x 8
  const int x0 = blockIdx.x * 32, y0 = blockIdx.y * 32;
#pragma unroll
  for (int i = 0; i < 32; i += 8)
    tile[ty + i][tx] = f2bf(W[(size_t)(y0 + ty + i) * 512 + x0 + tx]);
  __syncthreads();
#pragma unroll
  for (int i = 0; i < 32; i += 8)
    dst[(size_t)(x0 + ty + i) * 512 + y0 + tx] = tile[tx][ty + i];
}

// ---------------------------------------------------------------------------
// GEMM: C[M,Nd] = A[M,512] @ BT[Nd,512]^T (+bias), bf16 in, fp32 acc.
// Block tile 128 x BN (BN = 128 or 256), BK=64 as two 32-col panels.
// XCD swizzle: each XCD owns a band of 32 m-tiles, n swept fastest -> A-tile
// stays in that XCD's L2 across all its n-blocks.
// bf16 out -> LDS transpose for 256B-contiguous stores; fp32 out -> direct.
// ---------------------------------------------------------------------------
template <bool STORE_F32, int BN>
__global__ __launch_bounds__(256) void gemm_bt(
    const bf16_t* __restrict__ A,
    const bf16_t* __restrict__ BT,
    void* __restrict__ Cp,
    const float* __restrict__ bias,
    int Nd)
{
  constexpr int Kd = 512;
  constexpr int JT = BN / 32;                       // n-tiles (16 wide) per wave
  constexpr int RBW = BN / 4;                       // B rows staged per wave
  __shared__ __align__(16) bf16_t smem[8192 + 2 * BN * 32];
  bf16_t* const As[2] = { smem,        smem + 4096 };
  bf16_t* const Bs[2] = { smem + 8192, smem + 8192 + BN * 32 };

  const int tid  = threadIdx.x;
  const int lane = tid & 63, w = tid >> 6;
  const int quad = lane >> 4, r16 = lane & 15;

  // XCD-aware remap (8 XCDs, round-robin dispatch assumed; perf-only heuristic)
  const int G = gridDim.x;
  const int l = blockIdx.y * G + blockIdx.x;
  const int xcd = l & 7, slot = l >> 3;
  const int mb = xcd * (gridDim.y >> 3) + slot / G; // 32-m-tile band per XCD
  const int nb = slot % G;                          // n fastest: A-tile L2 reuse
  const int m0 = mb * 128, n0 = nb * BN;

  const int wm = (w & 1) * 64, wn = (w >> 1) * (BN / 2);

  f32x4 acc[4][JT] = {};

  // staging: lane -> (row=l>>2, 16B seg=l&3); wave w stages A rows [w*32,w*32+32),
  // B rows [w*RBW, w*RBW+RBW)
  const int rA = w * 32  + (lane >> 2);
  const int rB = w * RBW + (lane >> 2);
  const int sc = (lane & 3) * 8;
  const bf16_t* Ag = A  + (size_t)(m0 + rA) * Kd + sc;
  const bf16_t* Bg = BT + (size_t)(n0 + rB) * Kd + sc;

  for (int k0 = 0; k0 < Kd; k0 += 64) {
    __syncthreads();
#pragma unroll
    for (int ps = 0; ps < 2; ++ps) {
      const int kp = k0 + ps * 32;
      GLD16(Ag + kp,           As[ps] + w * 1024);
      GLD16(Ag + kp + 16 * Kd, As[ps] + w * 1024 + 512);
#pragma unroll
      for (int rr = 0; rr < BN / 64; ++rr)
        GLD16(Bg + kp + rr * 16 * Kd, Bs[ps] + w * RBW * 32 + rr * 512);
    }
    __builtin_amdgcn_s_waitcnt(0x0f70);   // vmcnt(0)
    __syncthreads();

#pragma unroll
    for (int ps = 0; ps < 2; ++ps) {
      bf16x8 af[4];
#pragma unroll
      for (int i = 0; i < 4; ++i)
        af[i] = *(const bf16x8*)&As[ps][(wm + i * 16 + r16) * 32 + quad * 8];
#pragma unroll
      for (int j = 0; j < JT; ++j) {
        bf16x8 bfr = *(const bf16x8*)&Bs[ps][(wn + j * 16 + r16) * 32 + quad * 8];
#pragma unroll
        for (int i = 0; i < 4; ++i)
          acc[i][j] = __builtin_amdgcn_mfma_f32_16x16x32_bf16(af[i], bfr, acc[i][j], 0, 0, 0);
      }
    }
  }

  // epilogue: D row = quad*4+reg, col = lane&15 (verified m89/m91 layout)
  if (STORE_F32) {
    // fp32: 16 lanes x 4B = 64B contiguous per quad-row -> full sectors, direct.
#pragma unroll
    for (int i = 0; i < 4; ++i) {
#pragma unroll
      for (int j = 0; j < JT; ++j) {
        const int row = m0 + wm + i * 16 + quad * 4;
        const int col = n0 + wn + j * 16 + r16;
        const float bv = bias ? bias[col] : 0.0f;
#pragma unroll
        for (int rg = 0; rg < 4; ++rg)
          ((float*)Cp)[(size_t)(row + rg) * Nd + col] = acc[i][j][rg] + bv;
      }
    }
  } else {
    // bf16: route 64-row halves through LDS (pitch BN+8: 16B-aligned rows),
    // then store 16B/lane, fully coalesced.
    constexpr int PITCH = BN + 8;
    bf16_t* Es = smem;                       // 64*PITCH fits in smem
#pragma unroll
    for (int p = 0; p < 2; ++p) {
      __syncthreads();
      if ((w & 1) == p) {
#pragma unroll
        for (int i = 0; i < 4; ++i)
#pragma unroll
          for (int j = 0; j < JT; ++j)
#pragma unroll
            for (int rg = 0; rg < 4; ++rg)
              Es[(i * 16 + quad * 4 + rg) * PITCH + wn + j * 16 + r16] = f2bf(acc[i][j][rg]);
      }
      __syncthreads();
      constexpr int TPR = BN / 8;            // threads per row (16B each)
      constexpr int RPI = 256 / TPR;         // rows per iteration
#pragma unroll
      for (int rd = 0; rd < 64 / RPI; ++rd) {
        const int row = rd * RPI + tid / TPR;
        const int col = (tid % TPR) * 8;
        *(bf16x8*)&((bf16_t*)Cp)[(size_t)(m0 + p * 64 + row) * Nd + n0 + col] =
            *(const bf16x8*)&Es[row * PITCH + col];
      }
    }
  }
}

// ---------------------------------------------------------------------------
// Criss-cross attention: one WG per (b, h, r) group; 64x64 scores.
// QKV interleaved [32768][1536] (Q|K|V sections of 512 cols each).
// S = Q K^T * 0.125 (MFMA) -> in-register softmax (x2 folded) -> O = P @ V
// with V staged TRANSPOSED (VsT[dd][k], pitch 70) so PV b-frags are b128 reads.
// Output via LDS for coalesced 128B stores.
// ---------------------------------------------------------------------------
__global__ __launch_bounds__(256) void cc_attn(
    const bf16_t* __restrict__ QKV, bf16_t* __restrict__ Aout)
{
  __shared__ __align__(16) bf16_t Qs[64 * 72];   // Q rows; later P
  __shared__ __align__(16) bf16_t Ks[64 * 72];   // K rows; later O epilogue
  __shared__ __align__(16) bf16_t VsT[64 * 70];  // V^T [dd][k]

  const int gidx = blockIdx.x;                   // 8*8*64 = 4096 groups
  const int r = gidx & 63, h = (gidx >> 6) & 7, b = gidx >> 9;
  const int tid = threadIdx.x, lane = tid & 63, w = tid >> 6;
  const int quad = lane >> 4, r16 = lane & 15;
  const size_t row0 = (size_t)b * 4096 + (size_t)r * 64;   // first token row of group

  // ---- stage: thread t -> (row=t>>2, 16-elem seg=t&3)
  {
    const int row = tid >> 2, seg = tid & 3;
    const bf16_t* gp = QKV + (row0 + row) * 1536 + h * 64 + seg * 16;
    *(bf16x8*)&Qs[row * 72 + seg * 16]     = *(const bf16x8*)&gp[0];
    *(bf16x8*)&Qs[row * 72 + seg * 16 + 8] = *(const bf16x8*)&gp[8];
    *(bf16x8*)&Ks[row * 72 + seg * 16]     = *(const bf16x8*)&gp[512];
    *(bf16x8*)&Ks[row * 72 + seg * 16 + 8] = *(const bf16x8*)&gp[520];
    bf16x8 v0 = *(const bf16x8*)&gp[1024];
    bf16x8 v1 = *(const bf16x8*)&gp[1032];
#pragma unroll
    for (int e = 0; e < 8; ++e) {
      VsT[(seg * 16 + e) * 70 + row]     = v0[e];   // VsT[dd][k=row]
      VsT[(seg * 16 + 8 + e) * 70 + row] = v1[e];
    }
  }
  __syncthreads();

  // ---- S = (Q K^T); wave w owns score rows [16w, 16w+16)
  f32x4 sacc[4] = {};
#pragma unroll
  for (int ks = 0; ks < 2; ++ks) {
    bf16x8 aq = *(const bf16x8*)&Qs[(w * 16 + r16) * 72 + ks * 32 + quad * 8];
#pragma unroll
    for (int nj = 0; nj < 4; ++nj) {
      bf16x8 bk = *(const bf16x8*)&Ks[(nj * 16 + r16) * 72 + ks * 32 + quad * 8];
      sacc[nj] = __builtin_amdgcn_mfma_f32_16x16x32_bf16(aq, bk, sacc[nj], 0, 0, 0);
    }
  }

  // ---- in-register softmax. Lane holds S[row=w*16+quad*4+rg][col=nj*16+r16]*0.125.
  float ex[4][4];                      // [nj][rg]
  float sm[4];
#pragma unroll
  for (int rg = 0; rg < 4; ++rg) {
    float m = -3.0e38f;
#pragma unroll
    for (int nj = 0; nj < 4; ++nj) {
      ex[nj][rg] = sacc[nj][rg] * 0.125f;
      m = fmaxf(m, ex[nj][rg]);
    }
    m = fmaxf(m, __shfl_xor(m, 1));
    m = fmaxf(m, __shfl_xor(m, 2));
    m = fmaxf(m, __shfl_xor(m, 4));
    m = fmaxf(m, __shfl_xor(m, 8));
    float s = 0.f;
#pragma unroll
    for (int nj = 0; nj < 4; ++nj) { ex[nj][rg] = __expf(ex[nj][rg] - m); s += ex[nj][rg]; }
    s += __shfl_xor(s, 1);
    s += __shfl_xor(s, 2);
    s += __shfl_xor(s, 4);
    s += __shfl_xor(s, 8);
    sm[rg] = 2.0f / s;                 // x2: row+col branches identical
  }

  __syncthreads();                     // all waves done reading Qs
#pragma unroll
  for (int nj = 0; nj < 4; ++nj)
#pragma unroll
    for (int rg = 0; rg < 4; ++rg)
      Qs[(w * 16 + quad * 4 + rg) * 72 + nj * 16 + r16] = f2bf(ex[nj][rg] * sm[rg]);
  __syncthreads();

  // ---- O = P @ V via VsT (b128 b-frags)
  f32x4 oacc[4] = {};
#pragma unroll
  for (int ks = 0; ks < 2; ++ks) {
    bf16x8 ap = *(const bf16x8*)&Qs[(w * 16 + r16) * 72 + ks * 32 + quad * 8];
#pragma unroll
    for (int nj = 0; nj < 4; ++nj) {
      bf16x8 bv = *(const bf16x8*)&VsT[(nj * 16 + r16) * 70 + ks * 32 + quad * 8];
      oacc[nj] = __builtin_amdgcn_mfma_f32_16x16x32_bf16(ap, bv, oacc[nj], 0, 0, 0);
    }
  }

  // ---- epilogue through LDS (reuse Ks, pitch 72) -> 128B-contiguous stores
  {
    bf16_t* Es = Ks;
#pragma unroll
    for (int nj = 0; nj < 4; ++nj)
#pragma unroll
      for (int rg = 0; rg < 4; ++rg)
        Es[(w * 16 + quad * 4 + rg) * 72 + nj * 16 + r16] = f2bf(oacc[nj][rg]);
    __syncthreads();
    const size_t obase = row0 * 512 + (size_t)h * 64;   // Aout [32768][512]
#pragma unroll
    for (int rd = 0; rd < 2; ++rd) {
      const int row = rd * 32 + (tid >> 3);
      const int col = (tid & 7) * 8;
      *(bf16x8*)&Aout[obase + (size_t)row * 512 + col] = *(const bf16x8*)&Es[row * 72 + col];
    }
  }
}

// ---------------------------------------------------------------------------
extern "C" void kernel_launch(void* const* d_in, const int* in_sizes, int n_in,
                              void* d_out, int out_size, void* d_ws, size_t ws_size,
                              hipStream_t stream)
{
  const float* x  = (const float*)d_in[0];
  const float* Wq = (const float*)d_in[1];
  const float* Wk = (const float*)d_in[2];
  const float* Wv = (const float*)d_in[3];
  const float* Wo = (const float*)d_in[4];
  const float* bo = (const float*)d_in[5];

  bf16_t* ws = (bf16_t*)d_ws;
  // workspace (bf16 elems):
  //   WT  : 4 x 262144   @ 0           (Wq|Wk|Wv rows 0..1535 stacked, then Wo)
  //   xbf : 16,777,216   @ 1,048,576   (dead after QKV GEMM; Ab aliases it)
  //   QKV : 50,331,648   @ 17,825,792  ([32768][1536] interleaved Q|K|V)
  // total 68,157,440 elems = 136,314,880 bytes
  bf16_t* WT  = ws;
  bf16_t* xbf = ws + 1048576;
  bf16_t* QKV = xbf + 16777216;
  bf16_t* Ab  = xbf;

  cvt_x<<<dim3(16384), 256, 0, stream>>>(x, xbf, 4194304);
  wt_kernel<<<dim3(16, 16, 4), dim3(32, 8), 0, stream>>>(Wq, Wk, Wv, Wo, WT);

  // fused QKV projection: B = stacked WTq|WTk|WTv (1536 rows), 128x256 tiles
  gemm_bt<false, 256><<<dim3(6, 256), 256, 0, stream>>>(xbf, WT, QKV, nullptr, 1536);

  cc_attn<<<dim3(4096), 256, 0, stream>>>(QKV, Ab);

  gemm_bt<true, 128><<<dim3(4, 256), 256, 0, stream>>>(Ab, WT + 786432, d_out, bo, 512);
}

// Round 6
// 257.300 us; speedup vs baseline: 1.1640x; 1.1640x over previous
//
#include <hip/hip_runtime.h>
#include <hip/hip_bf16.h>
#include <stdint.h>

// CrissCrossAttention, MI355X gfx950.
// out = 2 * row-attention (column branch collapses exactly onto row branch).
// Pipeline: cvt x->bf16 | transpose W->bf16 | fused QKV GEMM | per-(b,h,r) MFMA
//           attention | GEMM(+bias) -> fp32 out.
// r6: r4 structure (BN=128: 5 blocks/CU — r5's BN=256 cut residency 20->12 waves/CU
//     and regressed) + r5's XCD swizzle (proven: FETCH 141->44 MB on QKV GEMM).

typedef __bf16 bf16_t;
typedef __bf16 bf16x4v __attribute__((ext_vector_type(4)));
typedef __bf16 bf16x8 __attribute__((ext_vector_type(8)));
typedef float  f32x4  __attribute__((ext_vector_type(4)));

#define GLD16(gp, lp)                                                                  \
  __builtin_amdgcn_global_load_lds((__attribute__((address_space(1))) const void*)(gp),\
                                   (__attribute__((address_space(3))) void*)(lp),      \
                                   16, 0, 0)

__device__ __forceinline__ float  bf2f(bf16_t x) { return (float)x; }
__device__ __forceinline__ bf16_t f2bf(float x)  { return (bf16_t)x; }

// ---------------------------------------------------------------------------
// fp32 -> bf16 conversion, float4 loads.
// ---------------------------------------------------------------------------
__global__ __launch_bounds__(256) void cvt_x(const float* __restrict__ X,
                                             bf16_t* __restrict__ Y, int n4)
{
  int i = blockIdx.x * blockDim.x + threadIdx.x;
  if (i < n4) {
    float4 v = ((const float4*)X)[i];
    bf16x4v o;
    o[0] = f2bf(v.x); o[1] = f2bf(v.y); o[2] = f2bf(v.z); o[3] = f2bf(v.w);
    ((bf16x4v*)Y)[i] = o;
  }
}

// ---------------------------------------------------------------------------
// Weight transpose + cast: WT[n][k] = (bf16)W[k][n], 512x512, z selects matrix.
// ---------------------------------------------------------------------------
__global__ void wt_kernel(const float* __restrict__ Wq, const float* __restrict__ Wk,
                          const float* __restrict__ Wv, const float* __restrict__ Wo,
                          bf16_t* __restrict__ WT)
{
  __shared__ bf16_t tile[32][33];
  const int mat = blockIdx.z;
  const float* W = (mat == 0) ? Wq : (mat == 1) ? Wk : (mat == 2) ? Wv : Wo;
  bf16_t* dst = WT + (size_t)mat * 262144;
  const int tx = threadIdx.x, ty = threadIdx.y;          // 32 x 8
  const int x0 = blockIdx.x * 32, y0 = blockIdx.y * 32;
#pragma unroll
  for (int i = 0; i < 32; i += 8)
    tile[ty + i][tx] = f2bf(W[(size_t)(y0 + ty + i) * 512 + x0 + tx]);
  __syncthreads();
#pragma unroll
  for (int i = 0; i < 32; i += 8)
    dst[(size_t)(x0 + ty + i) * 512 + y0 + tx] = tile[tx][ty + i];
}

// ---------------------------------------------------------------------------
// GEMM: C[M,Nd] = A[M,512] @ BT[Nd,512]^T (+bias), bf16 in, fp32 acc.
// 128x128 tile, BK=64 as two 32-col panels.
// XCD swizzle (perf-only): each XCD owns a band of 32 m-tiles, n swept fastest
// -> A-tile (128KB) stays hot in that XCD's L2 across its n-blocks; B resident.
// bf16 out -> LDS transpose for 256B-contiguous stores; fp32 out -> direct.
// ---------------------------------------------------------------------------
template <bool STORE_F32>
__global__ __launch_bounds__(256) void gemm_bt(
    const bf16_t* __restrict__ A,
    const bf16_t* __restrict__ BT,
    void* __restrict__ Cp,
    const float* __restrict__ bias,
    int Nd)
{
  constexpr int Kd = 512;
  __shared__ __align__(16) bf16_t smem[16384];   // 4 staging panels 128x32
  bf16_t* const As[2] = { smem,        smem + 8192  };
  bf16_t* const Bs[2] = { smem + 4096, smem + 12288 };

  const int tid  = threadIdx.x;
  const int lane = tid & 63, w = tid >> 6;
  const int quad = lane >> 4, r16 = lane & 15;

  // XCD-aware remap (8 XCDs, round-robin dispatch; verified r5: FETCH 141->44MB)
  const int G = gridDim.x;
  const int l = blockIdx.y * G + blockIdx.x;
  const int xcd = l & 7, slot = l >> 3;
  const int mb = xcd * (gridDim.y >> 3) + slot / G; // m-tile band per XCD
  const int nb = slot % G;                          // n fastest: A-tile L2 reuse
  const int m0 = mb * 128, n0 = nb * 128;

  const int wm = (w & 1) * 64, wn = (w >> 1) * 64;

  f32x4 acc[4][4] = {};

  // staging: wave w stages rows [w*32, w*32+32); lane -> (row=l>>2, 16B seg=l&3)
  const int srow = w * 32 + (lane >> 2);
  const int scol = (lane & 3) * 8;
  const bf16_t* Ag = A  + (size_t)(m0 + srow) * Kd + scol;
  const bf16_t* Bg = BT + (size_t)(n0 + srow) * Kd + scol;

  for (int k0 = 0; k0 < Kd; k0 += 64) {
    __syncthreads();
    GLD16(Ag + k0,                As[0] + w * 1024);
    GLD16(Ag + k0 + 16 * Kd,      As[0] + w * 1024 + 512);
    GLD16(Bg + k0,                Bs[0] + w * 1024);
    GLD16(Bg + k0 + 16 * Kd,      Bs[0] + w * 1024 + 512);
    GLD16(Ag + k0 + 32,           As[1] + w * 1024);
    GLD16(Ag + k0 + 32 + 16 * Kd, As[1] + w * 1024 + 512);
    GLD16(Bg + k0 + 32,           Bs[1] + w * 1024);
    GLD16(Bg + k0 + 32 + 16 * Kd, Bs[1] + w * 1024 + 512);
    __builtin_amdgcn_s_waitcnt(0x0f70);   // vmcnt(0)
    __syncthreads();

#pragma unroll
    for (int ps = 0; ps < 2; ++ps) {
      bf16x8 af[4], bfr[4];
#pragma unroll
      for (int i = 0; i < 4; ++i)
        af[i] = *(const bf16x8*)&As[ps][(wm + i * 16 + r16) * 32 + quad * 8];
#pragma unroll
      for (int j = 0; j < 4; ++j)
        bfr[j] = *(const bf16x8*)&Bs[ps][(wn + j * 16 + r16) * 32 + quad * 8];
#pragma unroll
      for (int i = 0; i < 4; ++i)
#pragma unroll
        for (int j = 0; j < 4; ++j)
          acc[i][j] = __builtin_amdgcn_mfma_f32_16x16x32_bf16(af[i], bfr[j], acc[i][j], 0, 0, 0);
    }
  }

  // epilogue: D row = quad*4+reg, col = lane&15 (verified m89/m91 layout)
  if (STORE_F32) {
    // fp32: 16 lanes x 4B = 64B contiguous per quad-row -> full sectors, direct.
#pragma unroll
    for (int i = 0; i < 4; ++i) {
#pragma unroll
      for (int j = 0; j < 4; ++j) {
        const int row = m0 + wm + i * 16 + quad * 4;
        const int col = n0 + wn + j * 16 + r16;
        const float bv = bias ? bias[col] : 0.0f;
#pragma unroll
        for (int rg = 0; rg < 4; ++rg)
          ((float*)Cp)[(size_t)(row + rg) * Nd + col] = acc[i][j][rg] + bv;
      }
    }
  } else {
    // bf16: route 64-row halves through LDS (pitch 132) then 16B/lane stores,
    // 256B contiguous per 16 lanes (r4: killed the half-sector RMW, WRITE -> ideal).
    bf16_t* Es = smem;  // 64*132 = 8448 elems < 16384
#pragma unroll
    for (int p = 0; p < 2; ++p) {
      __syncthreads();
      if ((w & 1) == p) {
#pragma unroll
        for (int i = 0; i < 4; ++i)
#pragma unroll
          for (int j = 0; j < 4; ++j)
#pragma unroll
            for (int rg = 0; rg < 4; ++rg)
              Es[(i * 16 + quad * 4 + rg) * 132 + wn + j * 16 + r16] = f2bf(acc[i][j][rg]);
      }
      __syncthreads();
#pragma unroll
      for (int rd = 0; rd < 4; ++rd) {
        const int row = rd * 16 + (tid >> 4);
        const int col = (tid & 15) * 8;
        *(bf16x8*)&((bf16_t*)Cp)[(size_t)(m0 + p * 64 + row) * Nd + n0 + col] =
            *(const bf16x8*)&Es[row * 132 + col];
      }
    }
  }
}

// ---------------------------------------------------------------------------
// Criss-cross attention: one WG per (b, h, r) group; 64x64 scores.
// QKV interleaved [32768][1536] (Q|K|V sections of 512 cols each).
// S = Q K^T * 0.125 (MFMA) -> in-register softmax (x2 folded) -> O = P @ V
// with V staged TRANSPOSED (VsT[dd][k], pitch 70) so PV b-frags are b128 reads.
// Output via LDS for coalesced 128B stores.
// ---------------------------------------------------------------------------
__global__ __launch_bounds__(256) void cc_attn(
    const bf16_t* __restrict__ QKV, bf16_t* __restrict__ Aout)
{
  __shared__ __align__(16) bf16_t Qs[64 * 72];   // Q rows; later P
  __shared__ __align__(16) bf16_t Ks[64 * 72];   // K rows; later O epilogue
  __shared__ __align__(16) bf16_t VsT[64 * 70];  // V^T [dd][k]

  const int gidx = blockIdx.x;                   // 8*8*64 = 4096 groups
  const int r = gidx & 63, h = (gidx >> 6) & 7, b = gidx >> 9;
  const int tid = threadIdx.x, lane = tid & 63, w = tid >> 6;
  const int quad = lane >> 4, r16 = lane & 15;
  const size_t row0 = (size_t)b * 4096 + (size_t)r * 64;   // first token row of group

  // ---- stage: thread t -> (row=t>>2, 16-elem seg=t&3)
  {
    const int row = tid >> 2, seg = tid & 3;
    const bf16_t* gp = QKV + (row0 + row) * 1536 + h * 64 + seg * 16;
    *(bf16x8*)&Qs[row * 72 + seg * 16]     = *(const bf16x8*)&gp[0];
    *(bf16x8*)&Qs[row * 72 + seg * 16 + 8] = *(const bf16x8*)&gp[8];
    *(bf16x8*)&Ks[row * 72 + seg * 16]     = *(const bf16x8*)&gp[512];
    *(bf16x8*)&Ks[row * 72 + seg * 16 + 8] = *(const bf16x8*)&gp[520];
    bf16x8 v0 = *(const bf16x8*)&gp[1024];
    bf16x8 v1 = *(const bf16x8*)&gp[1032];
#pragma unroll
    for (int e = 0; e < 8; ++e) {
      VsT[(seg * 16 + e) * 70 + row]     = v0[e];   // VsT[dd][k=row]
      VsT[(seg * 16 + 8 + e) * 70 + row] = v1[e];
    }
  }
  __syncthreads();

  // ---- S = (Q K^T); wave w owns score rows [16w, 16w+16)
  f32x4 sacc[4] = {};
#pragma unroll
  for (int ks = 0; ks < 2; ++ks) {
    bf16x8 aq = *(const bf16x8*)&Qs[(w * 16 + r16) * 72 + ks * 32 + quad * 8];
#pragma unroll
    for (int nj = 0; nj < 4; ++nj) {
      bf16x8 bk = *(const bf16x8*)&Ks[(nj * 16 + r16) * 72 + ks * 32 + quad * 8];
      sacc[nj] = __builtin_amdgcn_mfma_f32_16x16x32_bf16(aq, bk, sacc[nj], 0, 0, 0);
    }
  }

  // ---- in-register softmax. Lane holds S[row=w*16+quad*4+rg][col=nj*16+r16]*0.125.
  float ex[4][4];                      // [nj][rg]
  float sm[4];
#pragma unroll
  for (int rg = 0; rg < 4; ++rg) {
    float m = -3.0e38f;
#pragma unroll
    for (int nj = 0; nj < 4; ++nj) {
      ex[nj][rg] = sacc[nj][rg] * 0.125f;
      m = fmaxf(m, ex[nj][rg]);
    }
    m = fmaxf(m, __shfl_xor(m, 1));
    m = fmaxf(m, __shfl_xor(m, 2));
    m = fmaxf(m, __shfl_xor(m, 4));
    m = fmaxf(m, __shfl_xor(m, 8));
    float s = 0.f;
#pragma unroll
    for (int nj = 0; nj < 4; ++nj) { ex[nj][rg] = __expf(ex[nj][rg] - m); s += ex[nj][rg]; }
    s += __shfl_xor(s, 1);
    s += __shfl_xor(s, 2);
    s += __shfl_xor(s, 4);
    s += __shfl_xor(s, 8);
    sm[rg] = 2.0f / s;                 // x2: row+col branches identical
  }

  __syncthreads();                     // all waves done reading Qs
#pragma unroll
  for (int nj = 0; nj < 4; ++nj)
#pragma unroll
    for (int rg = 0; rg < 4; ++rg)
      Qs[(w * 16 + quad * 4 + rg) * 72 + nj * 16 + r16] = f2bf(ex[nj][rg] * sm[rg]);
  __syncthreads();

  // ---- O = P @ V via VsT (b128 b-frags)
  f32x4 oacc[4] = {};
#pragma unroll
  for (int ks = 0; ks < 2; ++ks) {
    bf16x8 ap = *(const bf16x8*)&Qs[(w * 16 + r16) * 72 + ks * 32 + quad * 8];
#pragma unroll
    for (int nj = 0; nj < 4; ++nj) {
      bf16x8 bv = *(const bf16x8*)&VsT[(nj * 16 + r16) * 70 + ks * 32 + quad * 8];
      oacc[nj] = __builtin_amdgcn_mfma_f32_16x16x32_bf16(ap, bv, oacc[nj], 0, 0, 0);
    }
  }

  // ---- epilogue through LDS (reuse Ks, pitch 72) -> 128B-contiguous stores
  {
    bf16_t* Es = Ks;
#pragma unroll
    for (int nj = 0; nj < 4; ++nj)
#pragma unroll
      for (int rg = 0; rg < 4; ++rg)
        Es[(w * 16 + quad * 4 + rg) * 72 + nj * 16 + r16] = f2bf(oacc[nj][rg]);
    __syncthreads();
    const size_t obase = row0 * 512 + (size_t)h * 64;   // Aout [32768][512]
#pragma unroll
    for (int rd = 0; rd < 2; ++rd) {
      const int row = rd * 32 + (tid >> 3);
      const int col = (tid & 7) * 8;
      *(bf16x8*)&Aout[obase + (size_t)row * 512 + col] = *(const bf16x8*)&Es[row * 72 + col];
    }
  }
}

// ---------------------------------------------------------------------------
extern "C" void kernel_launch(void* const* d_in, const int* in_sizes, int n_in,
                              void* d_out, int out_size, void* d_ws, size_t ws_size,
                              hipStream_t stream)
{
  const float* x  = (const float*)d_in[0];
  const float* Wq = (const float*)d_in[1];
  const float* Wk = (const float*)d_in[2];
  const float* Wv = (const float*)d_in[3];
  const float* Wo = (const float*)d_in[4];
  const float* bo = (const float*)d_in[5];

  bf16_t* ws = (bf16_t*)d_ws;
  // workspace (bf16 elems):
  //   WT  : 4 x 262144   @ 0           (Wq|Wk|Wv rows 0..1535 stacked, then Wo)
  //   xbf : 16,777,216   @ 1,048,576   (dead after QKV GEMM; Ab aliases it)
  //   QKV : 50,331,648   @ 17,825,792  ([32768][1536] interleaved Q|K|V)
  // total 68,157,440 elems = 136,314,880 bytes
  bf16_t* WT  = ws;
  bf16_t* xbf = ws + 1048576;
  bf16_t* QKV = xbf + 16777216;
  bf16_t* Ab  = xbf;

  cvt_x<<<dim3(16384), 256, 0, stream>>>(x, xbf, 4194304);
  wt_kernel<<<dim3(16, 16, 4), dim3(32, 8), 0, stream>>>(Wq, Wk, Wv, Wo, WT);

  // fused QKV projection: B = stacked WTq|WTk|WTv (1536 rows), 128x128 tiles
  gemm_bt<false><<<dim3(12, 256), 256, 0, stream>>>(xbf, WT, QKV, nullptr, 1536);

  cc_attn<<<dim3(4096), 256, 0, stream>>>(QKV, Ab);

  gemm_bt<true><<<dim3(4, 256), 256, 0, stream>>>(Ab, WT + 786432, d_out, bo, 512);
}